// Round 14
// baseline (144.204 us; speedup 1.0000x reference)
//
#include <hip/hip_runtime.h>
#include <hip/hip_bf16.h>
#include <math.h>

#define B_  8
#define C_  512
#define N_  1024
#define NH_ 8
#define HD_ 64
#define C3_ 1536

typedef __bf16 bf16x8  __attribute__((ext_vector_type(8)));
typedef __bf16 bf16x4v __attribute__((ext_vector_type(4)));
typedef float  f32x4   __attribute__((ext_vector_type(4)));
typedef __hip_bfloat16 bf16;

__device__ __forceinline__ f32x4 mfma16(const bf16x8& a, const bf16x8& b, const f32x4& c) {
    return __builtin_amdgcn_mfma_f32_16x16x32_bf16(a, b, c, 0, 0, 0);
}

// async global->LDS, 16B per lane. LDS dest = wave-uniform base + lane*16.
__device__ __forceinline__ void ld_lds16(const bf16* g, bf16* l_uniform) {
    __builtin_amdgcn_global_load_lds(
        (const __attribute__((address_space(1))) void*)(uintptr_t)g,
        (__attribute__((address_space(3))) void*)(uintptr_t)l_uniform,
        16, 0, 0);
}

// ---------------- prep: x transpose + weight conversion, one launch ----------------
__global__ __launch_bounds__(256) void prep(const float* __restrict__ x,
                                            const float* __restrict__ Wq,
                                            const float* __restrict__ Wp,
                                            bf16* __restrict__ xb,
                                            bf16* __restrict__ Wqb,
                                            bf16* __restrict__ Wpb) {
    const int tid = threadIdx.x;
    if (blockIdx.x < 4096) {
        __shared__ float T[32][33];
        int t = blockIdx.x;
        const int n0 = (t & 31) * 32; t >>= 5;
        const int c0 = (t & 15) * 32; t >>= 4;
        const int b  = t;
        const int tx = tid & 31, ty = tid >> 5;
        const float* xp = x + ((size_t)b * C_ + c0) * N_ + n0;
#pragma unroll
        for (int l = 0; l < 4; ++l)
            T[ty + 8 * l][tx] = xp[(ty + 8 * l) * N_ + tx];      // coalesced along n
        __syncthreads();
        bf16* xo = xb + ((size_t)b * N_ + n0) * C_ + c0;
        const int row = tid >> 3, cq = (tid & 7) * 4;            // packed bf16x4 stores
        bf16x4v o;
#pragma unroll
        for (int i = 0; i < 4; ++i) o[i] = (__bf16)T[cq + i][row];
        *(bf16x4v*)(xo + row * C_ + cq) = o;
    } else {
        const int base = (blockIdx.x - 4096) * 1024 + tid * 4;
        const float* src;
        bf16* dst;
        int off;
        if (base < C3_ * C_) { src = Wq; dst = Wqb; off = base; }
        else                 { src = Wp; dst = Wpb; off = base - C3_ * C_; }
        f32x4 w = *(const f32x4*)(src + off);
        bf16x4v o;
#pragma unroll
        for (int i = 0; i < 4; ++i) o[i] = (__bf16)w[i];
        *(bf16x4v*)(dst + off) = o;
    }
}

// ---------------- QKV GEMM: 8192x1536x512, 128x128 tiles, LDS-staged ----------------
__global__ __launch_bounds__(256) void qkv_mfma(const bf16* __restrict__ xb,
                                                const bf16* __restrict__ Wqb,
                                                const float* __restrict__ bq,
                                                bf16* __restrict__ Qb,
                                                bf16* __restrict__ Kb,
                                                bf16* __restrict__ Vt) {
    __shared__ bf16 As[128 * 32];
    __shared__ bf16 Bs[128 * 32];
    __shared__ bf16 Vl[4][16][20];
    const int tid = threadIdx.x, w = tid >> 6, lane = tid & 63;
    const int lo = lane & 15, hi = lane >> 4;
    const int j0 = blockIdx.x * 128;
    const int m0 = blockIdx.y * 128;
    const int b  = m0 >> 10;

    const int srow = w * 32 + (lane >> 2);
    const int scol = (lane & 3) * 8;
    const bf16* gA = xb  + (size_t)(m0 + srow) * C_ + scol;
    const bf16* gB = Wqb + (size_t)(j0 + srow) * C_ + scol;
    bf16* lA = As + (w * 32) * 32;
    bf16* lB = Bs + (w * 32) * 32;

    f32x4 acc[4][4];
#pragma unroll
    for (int mt = 0; mt < 4; ++mt)
#pragma unroll
        for (int jt = 0; jt < 4; ++jt)
            acc[mt][jt] = (f32x4){0.f, 0.f, 0.f, 0.f};

    for (int k0 = 0; k0 < C_; k0 += 32) {
        ld_lds16(gA + k0, lA);
        ld_lds16(gA + (size_t)16 * C_ + k0, lA + 16 * 32);
        ld_lds16(gB + k0, lB);
        ld_lds16(gB + (size_t)16 * C_ + k0, lB + 16 * 32);
        __syncthreads();

        bf16x8 af[4], bfr[4];
#pragma unroll
        for (int mt = 0; mt < 4; ++mt)
            af[mt] = *(const bf16x8*)(As + ((w & 1) * 64 + mt * 16 + lo) * 32 + hi * 8);
#pragma unroll
        for (int jt = 0; jt < 4; ++jt)
            bfr[jt] = *(const bf16x8*)(Bs + ((w >> 1) * 64 + jt * 16 + lo) * 32 + hi * 8);
#pragma unroll
        for (int mt = 0; mt < 4; ++mt)
#pragma unroll
            for (int jt = 0; jt < 4; ++jt)
                acc[mt][jt] = mfma16(af[mt], bfr[jt], acc[mt][jt]);
        __syncthreads();
    }

    const int jb = (w >> 1) * 64;
    const int nbase = (m0 & 1023) + (w & 1) * 64;
#pragma unroll
    for (int jt = 0; jt < 4; ++jt) {
        const int j16 = j0 + jb + jt * 16;
        const float bias = bq[j16 + lo];
        if (j16 < 512) {
            const int h = j16 >> 6, d = (j16 & 63) + lo;
            bf16* qp = Qb + ((size_t)(b * NH_ + h) * N_) * HD_ + d;
#pragma unroll
            for (int mt = 0; mt < 4; ++mt)
#pragma unroll
                for (int r = 0; r < 4; ++r) {
                    int n = nbase + mt * 16 + hi * 4 + r;
                    qp[(size_t)n * HD_] = __float2bfloat16((acc[mt][jt][r] + bias) * 0.125f);
                }
        } else if (j16 < 1024) {
            const int jj = j16 - 512;
            const int h = jj >> 6, d = (jj & 63) + lo;
            bf16* kp = Kb + ((size_t)(b * NH_ + h) * N_) * HD_ + d;
#pragma unroll
            for (int mt = 0; mt < 4; ++mt)
#pragma unroll
                for (int r = 0; r < 4; ++r) {
                    int n = nbase + mt * 16 + hi * 4 + r;
                    kp[(size_t)n * HD_] = __float2bfloat16(acc[mt][jt][r] + bias);
                }
        } else {
            const int jj = j16 - 1024;
            const int h = jj >> 6, dbase = jj & 63;
            bf16* vp = Vt + ((size_t)(b * NH_ + h) * HD_ + dbase) * N_ + nbase;
#pragma unroll
            for (int mt = 0; mt < 4; ++mt) {
#pragma unroll
                for (int r = 0; r < 4; ++r)
                    Vl[w][hi * 4 + r][lo] = __float2bfloat16(acc[mt][jt][r] + bias);
#pragma unroll
                for (int r = 0; r < 4; ++r)
                    vp[(size_t)(hi * 4 + r) * N_ + mt * 16 + lo] = Vl[w][lo][hi * 4 + r];
            }
        }
    }
}

// ---------------- MFMA flash attention: block-shared staging, unpaired waves ----------------
// R12's block-shared LDS K/V staging + one q-tile per wave: 1024 blocks ->
// 4 blocks/CU, 16 waves/CU (2x R13), single-buffered staging (26.6 KB LDS so
// 4 blocks fit; cross-block overlap covers the staging drain, m114).
// Block group g owns q-tiles {g, g+16, g+32, g+48} -> uniform-ish block bounds.
// blockIdx = g*64 + bh -> XCD = bh & 7 (per-XCD K/V working set ~3 MB in L2).

__global__ __launch_bounds__(256) void attn_mfma(const bf16* __restrict__ Qb,
                                                 const bf16* __restrict__ Kb,
                                                 const bf16* __restrict__ Vt,
                                                 bf16* __restrict__ ao) {
    __shared__ bf16 Ks0[64 * 32], Ks1[64 * 32];   // [key][d-half]
    __shared__ bf16 Vs0[64 * 32], Vs1[64 * 32];   // [d][key-half]
    __shared__ __align__(16) bf16 Pl[4][2][16][40];

    const int tid  = threadIdx.x;
    const int wv   = tid >> 6;
    const int lane = tid & 63;
    const int lo   = lane & 15;
    const int hi   = lane >> 4;
    const int bh   = blockIdx.x & 63;            // XCD = bh & 7
    const int g    = blockIdx.x >> 6;            // 0..15
    const int qt   = g + 16 * wv;                // 0..63
    const int qw   = qt * 16;

    const bf16* Qh = Qb + (size_t)bh * N_ * HD_;
    const bf16* Kh = Kb + (size_t)bh * N_ * HD_;
    const bf16* Vh = Vt + (size_t)bh * HD_ * N_;

    const bf16x8 q0 = *(const bf16x8*)(Qh + (qw + lo) * HD_ + hi * 8);
    const bf16x8 q1 = *(const bf16x8*)(Qh + (qw + lo) * HD_ + 32 + hi * 8);

    // staging: 256 threads x 16B per call = one 64x32 half-tile
    const int srow = tid >> 2;
    const int scol = (tid & 3) * 8;
    const bf16* gK = Kh + (size_t)srow * HD_ + scol;
    const bf16* gV = Vh + (size_t)srow * N_ + scol;
    const int lofs = wv * 512;                   // wave-uniform LDS offset

    f32x4 O[4];
    float Lp[4];
#pragma unroll
    for (int r = 0; r < 4; ++r) {
        O[0][r] = O[1][r] = O[2][r] = O[3][r] = 0.f;
        Lp[r] = 0.f;
    }

    const int nkb    = (qw + 79) >> 6;                     // this wave's bound
    const int nkbBlk = ((g + 48) * 16 + 79) >> 6;          // block bound (wave 3)

    for (int kb = 0; kb < nkbBlk; ++kb) {
        const int key0 = kb * 64;

        ld_lds16(gK + (size_t)key0 * HD_,      Ks0 + lofs);
        ld_lds16(gK + (size_t)key0 * HD_ + 32, Ks1 + lofs);
        ld_lds16(gV + key0,                    Vs0 + lofs);
        ld_lds16(gV + key0 + 32,               Vs1 + lofs);
        __syncthreads();

        if (kb < nkb) {
            bf16x8 kf[4][2], vf[4][2];
#pragma unroll
            for (int t = 0; t < 4; ++t) {
                kf[t][0] = *(const bf16x8*)(Ks0 + (t * 16 + lo) * 32 + hi * 8);
                kf[t][1] = *(const bf16x8*)(Ks1 + (t * 16 + lo) * 32 + hi * 8);
                vf[t][0] = *(const bf16x8*)(Vs0 + (t * 16 + lo) * 32 + hi * 8);
                vf[t][1] = *(const bf16x8*)(Vs1 + (t * 16 + lo) * 32 + hi * 8);
            }

            f32x4 S[4];
#pragma unroll
            for (int t = 0; t < 4; ++t) {
                S[t] = (f32x4){0.f, 0.f, 0.f, 0.f};
                S[t] = mfma16(q0, kf[t][0], S[t]);
                S[t] = mfma16(q1, kf[t][1], S[t]);
            }

            if (key0 + 63 > qw) {
#pragma unroll
                for (int t = 0; t < 4; ++t)
#pragma unroll
                    for (int r = 0; r < 4; ++r)
                        if (key0 + t * 16 + lo > qw + hi * 4 + r) S[t][r] = -1e30f;
            }

#pragma unroll
            for (int t = 0; t < 4; ++t)
#pragma unroll
                for (int r = 0; r < 4; ++r) {
                    float p = __expf(S[t][r]);
                    Lp[r] += p;
                    Pl[wv][t >> 1][hi * 4 + r][(t & 1) * 16 + lo] = __float2bfloat16(p);
                }

            bf16x8 pa0 = *(const bf16x8*)(&Pl[wv][0][lo][hi * 8]);
            bf16x8 pa1 = *(const bf16x8*)(&Pl[wv][1][lo][hi * 8]);
#pragma unroll
            for (int t = 0; t < 4; ++t) {
                O[t] = mfma16(pa0, vf[t][0], O[t]);
                O[t] = mfma16(pa1, vf[t][1], O[t]);
            }
        }
        __syncthreads();
    }

    const int b = bh >> 3, h = bh & 7;
    float rL[4];
#pragma unroll
    for (int r = 0; r < 4; ++r) {
        float Ls = Lp[r];
#pragma unroll
        for (int off = 1; off < 16; off <<= 1)
            Ls += __shfl_xor(Ls, off, 64);
        rL[r] = 1.f / Ls;
    }
#pragma unroll
    for (int t = 0; t < 4; ++t)
#pragma unroll
        for (int r = 0; r < 4; ++r) {
            int q = qw + hi * 4 + r;
            ao[((size_t)b * N_ + q) * C_ + h * HD_ + t * 16 + lo] =
                __float2bfloat16(O[t][r] * rL[r]);
        }
}

// ---------------- Projection GEMM: 512x8192x512, 64j x 128n tiles, LDS-staged ----------------
__global__ __launch_bounds__(256) void proj_mfma(const bf16* __restrict__ aob,
                                                 const bf16* __restrict__ Wpb,
                                                 const float* __restrict__ bp,
                                                 float* __restrict__ out) {
    __shared__ bf16 As[64 * 32];
    __shared__ bf16 Bs[128 * 32];
    const int tid = threadIdx.x, w = tid >> 6, lane = tid & 63;
    const int lo = lane & 15, hi = lane >> 4;
    const int j0 = blockIdx.x * 64;
    const int n0 = blockIdx.y * 128;
    const int b  = n0 >> 10;

    const int r4 = lane >> 2, c8 = (lane & 3) * 8;
    const bf16* gA = Wpb + (size_t)(j0 + w * 16 + r4) * C_ + c8;
    const bf16* gB = aob + (size_t)(n0 + w * 32 + r4) * C_ + c8;
    bf16* lA = As + (w * 16) * 32;
    bf16* lB = Bs + (w * 32) * 32;

    f32x4 acc[2][4];
#pragma unroll
    for (int mt = 0; mt < 2; ++mt)
#pragma unroll
        for (int jt = 0; jt < 4; ++jt)
            acc[mt][jt] = (f32x4){0.f, 0.f, 0.f, 0.f};

    for (int k0 = 0; k0 < C_; k0 += 32) {
        ld_lds16(gA + k0, lA);
        ld_lds16(gB + k0, lB);
        ld_lds16(gB + (size_t)16 * C_ + k0, lB + 16 * 32);
        __syncthreads();

        bf16x8 af[2], bfr[4];
#pragma unroll
        for (int mt = 0; mt < 2; ++mt)
            af[mt] = *(const bf16x8*)(As + ((w & 1) * 32 + mt * 16 + lo) * 32 + hi * 8);
#pragma unroll
        for (int jt = 0; jt < 4; ++jt)
            bfr[jt] = *(const bf16x8*)(Bs + ((w >> 1) * 64 + jt * 16 + lo) * 32 + hi * 8);
#pragma unroll
        for (int mt = 0; mt < 2; ++mt)
#pragma unroll
            for (int jt = 0; jt < 4; ++jt)
                acc[mt][jt] = mfma16(af[mt], bfr[jt], acc[mt][jt]);
        __syncthreads();
    }

#pragma unroll
    for (int mt = 0; mt < 2; ++mt)
#pragma unroll
        for (int r = 0; r < 4; ++r) {
            const int j = j0 + (w & 1) * 32 + mt * 16 + hi * 4 + r;
            const float bias = bp[j];
            float* op = out + ((size_t)(b * C_ + j)) * N_ + (n0 & 1023) + (w >> 1) * 64 + lo;
#pragma unroll
            for (int jt = 0; jt < 4; ++jt)
                op[jt * 16] = acc[mt][jt][r] + bias;
        }
}

extern "C" void kernel_launch(void* const* d_in, const int* in_sizes, int n_in,
                              void* d_out, int out_size, void* d_ws, size_t ws_size,
                              hipStream_t stream) {
    const float* x  = (const float*)d_in[0];
    const float* Wq = (const float*)d_in[1];
    const float* bq = (const float*)d_in[2];
    const float* Wp = (const float*)d_in[3];
    const float* bp = (const float*)d_in[4];
    float* out = (float*)d_out;

    const size_t headElems = (size_t)B_ * NH_ * N_ * HD_;
    bf16* xb  = (bf16*)d_ws;
    bf16* Wqb = xb + (size_t)B_ * N_ * C_;
    bf16* Wpb = Wqb + (size_t)C3_ * C_;
    bf16* Qb  = Wpb + (size_t)C_ * C_;
    bf16* Kb  = Qb + headElems;
    bf16* Vt  = Kb + headElems;
    bf16* aob = Vt + headElems;

    prep<<<dim3(4096 + 1024), dim3(256), 0, stream>>>(x, Wq, Wp, xb, Wqb, Wpb);

    qkv_mfma<<<dim3(C3_ / 128, (B_ * N_) / 128), dim3(256), 0, stream>>>(xb, Wqb, bq, Qb, Kb, Vt);
    attn_mfma<<<dim3(16 * 64), dim3(256), 0, stream>>>(Qb, Kb, Vt, aob);
    proj_mfma<<<dim3(C_ / 64, (B_ * N_) / 128), dim3(256), 0, stream>>>(aob, Wpb, bp, out);
}